// Round 5
// baseline (875.362 us; speedup 1.0000x reference)
//
#include <hip/hip_runtime.h>

typedef _Float16 half8  __attribute__((ext_vector_type(8)));
typedef _Float16 half4_t __attribute__((ext_vector_type(4)));
typedef __fp16   fp16x2 __attribute__((ext_vector_type(2)));
typedef float    f32x4  __attribute__((ext_vector_type(4)));

union I4H8 { int i[4]; half8 h; };
union PKU  { fp16x2 h; int i; };
union PK2  { fp16x2 h[2]; int i[2]; half4_t h4; };

// swizzled token-LDS index (halves). XOR bits are multiples of 8 halves (16 B),
// so 16B ds_read_b128 chunks stay contiguous; 4-half runs (8B) also survive.
__device__ __forceinline__ int tokIdx(int r, int c) { return r*256 + (c ^ ((r & 7) << 3)); }

// generic 32x16 C-fragment transpose: C[row(in-reg)][col(l15)] -> F[col l15][row g*8+j].
__device__ __forceinline__ half8 xpose8(int a0, int a1, int b0, int b1,
                                        int sA, int sB, bool msel) {
  const int t0 = __shfl(a0, sA, 64);
  const int t1 = __shfl(b0, sA, 64);
  const int t2 = __shfl(a1, sA, 64);
  const int t3 = __shfl(b1, sA, 64);
  const int t4 = __shfl(a0, sB, 64);
  const int t5 = __shfl(b0, sB, 64);
  const int t6 = __shfl(a1, sB, 64);
  const int t7 = __shfl(b1, sB, 64);
  I4H8 u;
  u.i[0] = msel ? t1 : t0;
  u.i[1] = msel ? t3 : t2;
  u.i[2] = msel ? t5 : t4;
  u.i[3] = msel ? t7 : t6;
  return u.h;
}

__global__ void __launch_bounds__(256)
wconv_kernel(const float* __restrict__ wq, const float* __restrict__ wp,
             _Float16* __restrict__ o)
{
  const int i = blockIdx.x * 256 + threadIdx.x;
  if (i < 768*256) o[i] = (_Float16)wq[i];
  else             o[i] = (_Float16)wp[i - 768*256];
}

// 512 threads = 8 waves; one head per wave; one 8x8 window per block.
__global__ void __launch_bounds__(512, 4)
attn_kernel(const float* __restrict__ x,
            const float* __restrict__ b_qkv,
            const float* __restrict__ b_proj,
            const _Float16* __restrict__ w16,
            float* __restrict__ out)
{
  __shared__ __align__(16) _Float16 tok[64*256];   // 32 KB total LDS

  const int tid  = threadIdx.x;
  const int lane = tid & 63;
  const int w    = tid >> 6;        // wave 0..7 == head
  const int l15  = lane & 15;
  const int g    = lane >> 4;

  const int wid = blockIdx.x;
  const int b   = wid / (24*24);
  const int wh  = (wid / 24) % 24;
  const int ww  = wid % 24;
  const long long base = (((long long)b*192 + wh*8)*192 + ww*8)*256;

  // ---------------- stage tokens -> LDS fp16 (swizzled); 8 rows/wave ----------------
#pragma unroll
  for (int i = 0; i < 8; ++i) {
    const int tk = w*8 + i;
    const float4 v = *(const float4*)(x + base + ((tk >> 3)*192 + (tk & 7))*256 + lane*4);
    half4_t h;
    h[0] = (_Float16)v.x; h[1] = (_Float16)v.y;
    h[2] = (_Float16)v.z; h[3] = (_Float16)v.w;
    *(half4_t*)(tok + tk*256 + ((lane*4) ^ ((tk & 7) << 3))) = h;
  }
  __syncthreads();

  const _Float16* wqkv16  = w16;
  const _Float16* wproj16 = w16 + 768*256;

  const int srcA  = l15 | ((2*(g & 1)    ) << 4);
  const int srcB  = l15 | ((2*(g & 1) + 1) << 4);
  const bool misel = (g >> 1) != 0;

  const int hd = w;   // head index

  // -------- Q^T = Wq * X^T   (M=32 d, N=64 q, K=256) --------
  int qtp[2][4][2];
  {
    f32x4 qa[2][4];
#pragma unroll
    for (int mi = 0; mi < 2; ++mi)
#pragma unroll
      for (int ni = 0; ni < 4; ++ni) qa[mi][ni] = (f32x4)0.0f;
#pragma unroll
    for (int kk = 0; kk < 8; ++kk) {
      half8 aw[2], bt[4];
#pragma unroll
      for (int mi = 0; mi < 2; ++mi)
        aw[mi] = *(const half8*)(wqkv16 + (hd*32 + mi*16 + l15)*256 + kk*32 + g*8);
#pragma unroll
      for (int ni = 0; ni < 4; ++ni)
        bt[ni] = *(const half8*)(tok + tokIdx(ni*16 + l15, kk*32 + g*8));
#pragma unroll
      for (int mi = 0; mi < 2; ++mi)
#pragma unroll
        for (int ni = 0; ni < 4; ++ni)
          qa[mi][ni] = __builtin_amdgcn_mfma_f32_16x16x32_f16(aw[mi], bt[ni], qa[mi][ni], 0, 0, 0);
    }
#pragma unroll
    for (int mi = 0; mi < 2; ++mi) {
      float bq[4];
#pragma unroll
      for (int r = 0; r < 4; ++r) bq[r] = b_qkv[hd*32 + mi*16 + g*4 + r];
#pragma unroll
      for (int ni = 0; ni < 4; ++ni) {
        PKU u0, u1;
        u0.h = __builtin_amdgcn_cvt_pkrtz(qa[mi][ni][0] + bq[0], qa[mi][ni][1] + bq[1]);
        u1.h = __builtin_amdgcn_cvt_pkrtz(qa[mi][ni][2] + bq[2], qa[mi][ni][3] + bq[3]);
        qtp[mi][ni][0] = u0.i; qtp[mi][ni][1] = u1.i;
      }
    }
  }

  // -------- K^T = Wk * X^T   (M=32 d, N=64 k, K=256) --------
  half8 ka[4];
  {
    f32x4 kc[2][4];
#pragma unroll
    for (int mi = 0; mi < 2; ++mi)
#pragma unroll
      for (int ni = 0; ni < 4; ++ni) kc[mi][ni] = (f32x4)0.0f;
#pragma unroll
    for (int kk = 0; kk < 8; ++kk) {
      half8 aw[2], bt[4];
#pragma unroll
      for (int mi = 0; mi < 2; ++mi)
        aw[mi] = *(const half8*)(wqkv16 + (256 + hd*32 + mi*16 + l15)*256 + kk*32 + g*8);
#pragma unroll
      for (int ni = 0; ni < 4; ++ni)
        bt[ni] = *(const half8*)(tok + tokIdx(ni*16 + l15, kk*32 + g*8));
#pragma unroll
      for (int mi = 0; mi < 2; ++mi)
#pragma unroll
        for (int ni = 0; ni < 4; ++ni)
          kc[mi][ni] = __builtin_amdgcn_mfma_f32_16x16x32_f16(aw[mi], bt[ni], kc[mi][ni], 0, 0, 0);
    }
    int ktp[2][4][2];
#pragma unroll
    for (int mi = 0; mi < 2; ++mi) {
      float bk[4];
#pragma unroll
      for (int r = 0; r < 4; ++r) bk[r] = b_qkv[256 + hd*32 + mi*16 + g*4 + r];
#pragma unroll
      for (int ni = 0; ni < 4; ++ni) {
        PKU u0, u1;
        u0.h = __builtin_amdgcn_cvt_pkrtz(kc[mi][ni][0] + bk[0], kc[mi][ni][1] + bk[1]);
        u1.h = __builtin_amdgcn_cvt_pkrtz(kc[mi][ni][2] + bk[2], kc[mi][ni][3] + bk[3]);
        ktp[mi][ni][0] = u0.i; ktp[mi][ni][1] = u1.i;
      }
    }
#pragma unroll
    for (int MI = 0; MI < 4; ++MI)
      ka[MI] = xpose8(ktp[0][MI][0], ktp[0][MI][1], ktp[1][MI][0], ktp[1][MI][1],
                      srcA, srcB, misel);
  }

  // -------- S^T = K * Q^T  (M=64 key, N=64 q, K=32) + softmax --------
  int pk[4][4][2];
  float rv[4];
  {
    f32x4 s[4][4];
#pragma unroll
    for (int MI = 0; MI < 4; ++MI)
#pragma unroll
      for (int ni = 0; ni < 4; ++ni) s[MI][ni] = (f32x4)0.0f;
#pragma unroll
    for (int ni = 0; ni < 4; ++ni) {
      const half8 qb = xpose8(qtp[0][ni][0], qtp[0][ni][1], qtp[1][ni][0], qtp[1][ni][1],
                              srcA, srcB, misel);
#pragma unroll
      for (int MI = 0; MI < 4; ++MI)
        s[MI][ni] = __builtin_amdgcn_mfma_f32_16x16x32_f16(ka[MI], qb, s[MI][ni], 0, 0, 0);
    }

    const float alpha = 0.17677669529663687f;   // 1/sqrt(32)
#pragma unroll
    for (int ni = 0; ni < 4; ++ni) {
      float m = s[0][ni][0];
#pragma unroll
      for (int MI = 0; MI < 4; ++MI)
#pragma unroll
        for (int r = 0; r < 4; ++r) m = fmaxf(m, s[MI][ni][r]);
      m = fmaxf(m, __shfl_xor(m, 16, 64));
      m = fmaxf(m, __shfl_xor(m, 32, 64));
      float sum = 0.0f;
#pragma unroll
      for (int MI = 0; MI < 4; ++MI)
#pragma unroll
        for (int r = 0; r < 4; ++r) {
          const float e = __expf((s[MI][ni][r] - m) * alpha);
          sum += e;
          s[MI][ni][r] = e;
        }
      sum += __shfl_xor(sum, 16, 64);
      sum += __shfl_xor(sum, 32, 64);
      rv[ni] = 1.0f / sum;
#pragma unroll
      for (int MI = 0; MI < 4; ++MI) {
        PKU u0, u1;
        u0.h = __builtin_amdgcn_cvt_pkrtz(s[MI][ni][0], s[MI][ni][1]);
        u1.h = __builtin_amdgcn_cvt_pkrtz(s[MI][ni][2], s[MI][ni][3]);
        pk[MI][ni][0] = u0.i;
        pk[MI][ni][1] = u1.i;
      }
    }
  }

  // -------- V = X * Wv^T   (M=64 tok, N=32 d, K=256) --------
  int vpk[4][2][2];
  {
    f32x4 vv[4][2];
#pragma unroll
    for (int mi = 0; mi < 4; ++mi)
#pragma unroll
      for (int ni = 0; ni < 2; ++ni) vv[mi][ni] = (f32x4)0.0f;
#pragma unroll
    for (int kk = 0; kk < 8; ++kk) {
      half8 xt[4], wv[2];
#pragma unroll
      for (int mi = 0; mi < 4; ++mi)
        xt[mi] = *(const half8*)(tok + tokIdx(mi*16 + l15, kk*32 + g*8));
#pragma unroll
      for (int ni = 0; ni < 2; ++ni)
        wv[ni] = *(const half8*)(wqkv16 + (512 + hd*32 + ni*16 + l15)*256 + kk*32 + g*8);
#pragma unroll
      for (int mi = 0; mi < 4; ++mi)
#pragma unroll
        for (int ni = 0; ni < 2; ++ni)
          vv[mi][ni] = __builtin_amdgcn_mfma_f32_16x16x32_f16(xt[mi], wv[ni], vv[mi][ni], 0, 0, 0);
    }
#pragma unroll
    for (int ni = 0; ni < 2; ++ni) {
      const float bv = b_qkv[512 + hd*32 + ni*16 + l15];
#pragma unroll
      for (int mi = 0; mi < 4; ++mi) {
        PKU u0, u1;
        u0.h = __builtin_amdgcn_cvt_pkrtz(vv[mi][ni][0] + bv, vv[mi][ni][1] + bv);
        u1.h = __builtin_amdgcn_cvt_pkrtz(vv[mi][ni][2] + bv, vv[mi][ni][3] + bv);
        vpk[mi][ni][0] = u0.i;
        vpk[mi][ni][1] = u1.i;
      }
    }
  }

  // -------- O^T = V^T * P^T   (M=32 d, N=64 q, K=64), pack immediately --------
  int ohp[2][4][2];
  {
    f32x4 oh[2][4];
#pragma unroll
    for (int MI = 0; MI < 2; ++MI)
#pragma unroll
      for (int ni = 0; ni < 4; ++ni) oh[MI][ni] = (f32x4)0.0f;
#pragma unroll
    for (int kk = 0; kk < 2; ++kk) {
      half8 va[2];
#pragma unroll
      for (int MI = 0; MI < 2; ++MI)
        va[MI] = xpose8(vpk[2*kk][MI][0], vpk[2*kk][MI][1],
                        vpk[2*kk+1][MI][0], vpk[2*kk+1][MI][1], srcA, srcB, misel);
#pragma unroll
      for (int ni = 0; ni < 4; ++ni) {
        const half8 pb = xpose8(pk[2*kk][ni][0], pk[2*kk][ni][1],
                                pk[2*kk+1][ni][0], pk[2*kk+1][ni][1], srcA, srcB, misel);
#pragma unroll
        for (int MI = 0; MI < 2; ++MI)
          oh[MI][ni] = __builtin_amdgcn_mfma_f32_16x16x32_f16(va[MI], pb, oh[MI][ni], 0, 0, 0);
      }
    }
#pragma unroll
    for (int MI = 0; MI < 2; ++MI)
#pragma unroll
      for (int ni = 0; ni < 4; ++ni) {
        PK2 u;
        u.h[0] = __builtin_amdgcn_cvt_pkrtz(oh[MI][ni][0] * rv[ni], oh[MI][ni][1] * rv[ni]);
        u.h[1] = __builtin_amdgcn_cvt_pkrtz(oh[MI][ni][2] * rv[ni], oh[MI][ni][3] * rv[ni]);
        ohp[MI][ni][0] = u.i[0];
        ohp[MI][ni][1] = u.i[1];
      }
  }

  __syncthreads();   // all waves done reading tok

  // ---------------- write attention output into LDS (aliases tok), b64 ----------------
#pragma unroll
  for (int MI = 0; MI < 2; ++MI)
#pragma unroll
    for (int ni = 0; ni < 4; ++ni) {
      PK2 u;
      u.i[0] = ohp[MI][ni][0];
      u.i[1] = ohp[MI][ni][1];
      *(half4_t*)(tok + tokIdx(ni*16 + l15, hd*32 + MI*16 + g*4)) = u.h4;
    }
  __syncthreads();

  // ---------------- proj: out = AO * Wp^T + bp  (M=64, N=32/wave, K=256) ----------------
  f32x4 pa[4][2];
#pragma unroll
  for (int mi = 0; mi < 4; ++mi)
#pragma unroll
    for (int ni = 0; ni < 2; ++ni) pa[mi][ni] = (f32x4)0.0f;

#pragma unroll
  for (int kk = 0; kk < 8; ++kk) {
    half8 af[4], bf[2];
#pragma unroll
    for (int mi = 0; mi < 4; ++mi)
      af[mi] = *(const half8*)(tok + tokIdx(mi*16 + l15, kk*32 + g*8));
#pragma unroll
    for (int ni = 0; ni < 2; ++ni)
      bf[ni] = *(const half8*)(wproj16 + (w*32 + ni*16 + l15)*256 + kk*32 + g*8);
#pragma unroll
    for (int mi = 0; mi < 4; ++mi)
#pragma unroll
      for (int ni = 0; ni < 2; ++ni)
        pa[mi][ni] = __builtin_amdgcn_mfma_f32_16x16x32_f16(af[mi], bf[ni], pa[mi][ni], 0, 0, 0);
  }

#pragma unroll
  for (int ni = 0; ni < 2; ++ni) {
    const float bb = b_proj[w*32 + ni*16 + l15];
#pragma unroll
    for (int mi = 0; mi < 4; ++mi)
#pragma unroll
      for (int r = 0; r < 4; ++r) pa[mi][ni][r] += bb;
  }

  // ---------------- staged vectorized output: 2 passes of 32 rows ----------------
  float* tokF = (float*)tok;   // [32][256] f32, swizzled (aliases tok)
#pragma unroll
  for (int p = 0; p < 2; ++p) {
    __syncthreads();   // p=0: proj reads of tok done; p=1: pass-0 reads done
#pragma unroll
    for (int mh = 0; mh < 2; ++mh) {
      const int mi = 2*p + mh;
#pragma unroll
      for (int ni = 0; ni < 2; ++ni)
#pragma unroll
        for (int r = 0; r < 4; ++r) {
          const int tr = mh*16 + g*4 + r;
          tokF[tr*256 + ((w*32 + ni*16 + l15) ^ ((tr & 7) << 2))] = pa[mi][ni][r];
        }
    }
    __syncthreads();
    const int tr = tid >> 4;                   // 0..31: row within pass
    const int t  = p*32 + tr;                  // token
    const long long rowbase = base + ((long long)(t >> 3)*192 + (t & 7))*256;
#pragma unroll
    for (int k = 0; k < 4; ++k) {
      const int c = (tid & 15)*4 + k*64;
      const f32x4 v4 = *(const f32x4*)(tokF + tr*256 + (c ^ ((tr & 7) << 2)));
      *(f32x4*)(out + rowbase + c) = v4;
    }
  }
}

extern "C" void kernel_launch(void* const* d_in, const int* in_sizes, int n_in,
                              void* d_out, int out_size, void* d_ws, size_t ws_size,
                              hipStream_t stream) {
  const float* x      = (const float*)d_in[0];
  const float* w_qkv  = (const float*)d_in[1];
  const float* b_qkv  = (const float*)d_in[2];
  const float* w_proj = (const float*)d_in[3];
  const float* b_proj = (const float*)d_in[4];
  float* out = (float*)d_out;
  _Float16* w16 = (_Float16*)d_ws;

  wconv_kernel<<<1024, 256, 0, stream>>>(w_qkv, w_proj, w16);
  attn_kernel<<<4608, 512, 0, stream>>>(x, b_qkv, b_proj, w16, out);
}

// Round 6
// 529.958 us; speedup vs baseline: 1.6518x; 1.6518x over previous
//
#include <hip/hip_runtime.h>

typedef _Float16 half8  __attribute__((ext_vector_type(8)));
typedef _Float16 half4_t __attribute__((ext_vector_type(4)));
typedef __fp16   fp16x2 __attribute__((ext_vector_type(2)));
typedef float    f32x4  __attribute__((ext_vector_type(4)));

union I4H8 { int i[4]; half8 h; };
union PKU  { fp16x2 h; int i; };
union PK2  { fp16x2 h[2]; int i[2]; half4_t h4; };

// swizzled token-LDS index (halves). XOR bits are multiples of 8 halves (16 B),
// so 16B ds_read_b128 chunks stay contiguous; 4-half runs (8B) also survive.
__device__ __forceinline__ int tokIdx(int r, int c) { return r*256 + (c ^ ((r & 7) << 3)); }

// C-fragment (rows in-reg, cols on l15) -> A/B-fragment (cols in-reg, rows kept on l15).
__device__ __forceinline__ half8 xpose8(int a0, int a1, int b0, int b1,
                                        int sA, int sB, bool msel) {
  const int t0 = __shfl(a0, sA, 64);
  const int t1 = __shfl(b0, sA, 64);
  const int t2 = __shfl(a1, sA, 64);
  const int t3 = __shfl(b1, sA, 64);
  const int t4 = __shfl(a0, sB, 64);
  const int t5 = __shfl(b0, sB, 64);
  const int t6 = __shfl(a1, sB, 64);
  const int t7 = __shfl(b1, sB, 64);
  I4H8 u;
  u.i[0] = msel ? t1 : t0;
  u.i[1] = msel ? t3 : t2;
  u.i[2] = msel ? t5 : t4;
  u.i[3] = msel ? t7 : t6;
  return u.h;
}

__global__ void __launch_bounds__(256)
wconv_kernel(const float* __restrict__ wq, const float* __restrict__ wp,
             _Float16* __restrict__ o)
{
  const int i = blockIdx.x * 256 + threadIdx.x;
  if (i < 768*256) o[i] = (_Float16)wq[i];
  else             o[i] = (_Float16)wp[i - 768*256];
}

// 256 threads = 4 waves; 2 heads per wave; one 8x8 window per block.
// (256,2): proven no-spill config — unified reg budget ~256/wave.
__global__ void __launch_bounds__(256, 2)
attn_kernel(const float* __restrict__ x,
            const float* __restrict__ b_qkv,
            const float* __restrict__ b_proj,
            const _Float16* __restrict__ w16,
            float* __restrict__ out)
{
  __shared__ __align__(16) _Float16 tok[64*256];   // 32 KB total LDS

  const int tid  = threadIdx.x;
  const int lane = tid & 63;
  const int w    = tid >> 6;
  const int l15  = lane & 15;
  const int g    = lane >> 4;

  const int wid = blockIdx.x;
  const int b   = wid / (24*24);
  const int wh  = (wid / 24) % 24;
  const int ww  = wid % 24;
  const long long base = (((long long)b*192 + wh*8)*192 + ww*8)*256;

  // ---------------- stage tokens -> LDS fp16 (swizzled); 16 rows/wave ----------------
#pragma unroll
  for (int i = 0; i < 16; ++i) {
    const int tk = w*16 + i;
    const float4 v = *(const float4*)(x + base + ((tk >> 3)*192 + (tk & 7))*256 + lane*4);
    half4_t h;
    h[0] = (_Float16)v.x; h[1] = (_Float16)v.y;
    h[2] = (_Float16)v.z; h[3] = (_Float16)v.w;
    *(half4_t*)(tok + tk*256 + ((lane*4) ^ ((tk & 7) << 3))) = h;
  }
  __syncthreads();

  const _Float16* wqkv16  = w16;
  const _Float16* wproj16 = w16 + 768*256;

  const int srcA  = l15 | ((2*(g & 1)    ) << 4);
  const int srcB  = l15 | ((2*(g & 1) + 1) << 4);
  const bool misel = (g >> 1) != 0;

  int ohp[2][2][4][2];   // packed fp16 O^T fragments, both heads (32 ints)

#pragma unroll
  for (int hi = 0; hi < 2; ++hi) {
    const int hd = 2*w + hi;

    // ======== merged QKV:  Q^T,K^T = W*X^T (M=32 d, N=64)  and  V = X*Wv^T (M=64, N=32 d)
    // tok fragments bt[] serve as B for Q/K and as A for V (identical layouts).
    f32x4 qa[2][4], kc[2][4], vv[4][2];
#pragma unroll
    for (int mi = 0; mi < 2; ++mi)
#pragma unroll
      for (int ni = 0; ni < 4; ++ni) { qa[mi][ni] = (f32x4)0.0f; kc[mi][ni] = (f32x4)0.0f; }
#pragma unroll
    for (int mi = 0; mi < 4; ++mi)
#pragma unroll
      for (int ni = 0; ni < 2; ++ni) vv[mi][ni] = (f32x4)0.0f;

#pragma unroll
    for (int kk = 0; kk < 8; ++kk) {
      half8 bt[4], aw[4], wv[2];
#pragma unroll
      for (int ni = 0; ni < 4; ++ni)
        bt[ni] = *(const half8*)(tok + tokIdx(ni*16 + l15, kk*32 + g*8));
#pragma unroll
      for (int mi = 0; mi < 2; ++mi) {
        aw[mi]     = *(const half8*)(wqkv16 + (      hd*32 + mi*16 + l15)*256 + kk*32 + g*8);
        aw[2 + mi] = *(const half8*)(wqkv16 + (256 + hd*32 + mi*16 + l15)*256 + kk*32 + g*8);
        wv[mi]     = *(const half8*)(wqkv16 + (512 + hd*32 + mi*16 + l15)*256 + kk*32 + g*8);
      }
#pragma unroll
      for (int mi = 0; mi < 2; ++mi)
#pragma unroll
        for (int ni = 0; ni < 4; ++ni) {
          qa[mi][ni] = __builtin_amdgcn_mfma_f32_16x16x32_f16(aw[mi],     bt[ni], qa[mi][ni], 0, 0, 0);
          kc[mi][ni] = __builtin_amdgcn_mfma_f32_16x16x32_f16(aw[2 + mi], bt[ni], kc[mi][ni], 0, 0, 0);
        }
#pragma unroll
      for (int mi = 0; mi < 4; ++mi)
#pragma unroll
        for (int ni = 0; ni < 2; ++ni)
          vv[mi][ni] = __builtin_amdgcn_mfma_f32_16x16x32_f16(bt[mi], wv[ni], vv[mi][ni], 0, 0, 0);
    }

    // pack Q^T (rows = d in-reg) with bias
    int qtp[2][4][2];
#pragma unroll
    for (int mi = 0; mi < 2; ++mi) {
      float bq[4];
#pragma unroll
      for (int r = 0; r < 4; ++r) bq[r] = b_qkv[hd*32 + mi*16 + g*4 + r];
#pragma unroll
      for (int ni = 0; ni < 4; ++ni) {
        PKU u0, u1;
        u0.h = __builtin_amdgcn_cvt_pkrtz(qa[mi][ni][0] + bq[0], qa[mi][ni][1] + bq[1]);
        u1.h = __builtin_amdgcn_cvt_pkrtz(qa[mi][ni][2] + bq[2], qa[mi][ni][3] + bq[3]);
        qtp[mi][ni][0] = u0.i; qtp[mi][ni][1] = u1.i;
      }
    }

    // pack K^T with bias, transpose to S-GEMM A-fragments (rows = key tokens)
    half8 ka[4];
    {
      int ktp[2][4][2];
#pragma unroll
      for (int mi = 0; mi < 2; ++mi) {
        float bk[4];
#pragma unroll
        for (int r = 0; r < 4; ++r) bk[r] = b_qkv[256 + hd*32 + mi*16 + g*4 + r];
#pragma unroll
        for (int ni = 0; ni < 4; ++ni) {
          PKU u0, u1;
          u0.h = __builtin_amdgcn_cvt_pkrtz(kc[mi][ni][0] + bk[0], kc[mi][ni][1] + bk[1]);
          u1.h = __builtin_amdgcn_cvt_pkrtz(kc[mi][ni][2] + bk[2], kc[mi][ni][3] + bk[3]);
          ktp[mi][ni][0] = u0.i; ktp[mi][ni][1] = u1.i;
        }
      }
#pragma unroll
      for (int MI = 0; MI < 4; ++MI)
        ka[MI] = xpose8(ktp[0][MI][0], ktp[0][MI][1], ktp[1][MI][0], ktp[1][MI][1],
                        srcA, srcB, misel);
    }

    // pack V (rows = tok in-reg, cols = d on l15) with col-indexed bias
    int vpk[4][2][2];
#pragma unroll
    for (int ni = 0; ni < 2; ++ni) {
      const float bv = b_qkv[512 + hd*32 + ni*16 + l15];
#pragma unroll
      for (int mi = 0; mi < 4; ++mi) {
        PKU u0, u1;
        u0.h = __builtin_amdgcn_cvt_pkrtz(vv[mi][ni][0] + bv, vv[mi][ni][1] + bv);
        u1.h = __builtin_amdgcn_cvt_pkrtz(vv[mi][ni][2] + bv, vv[mi][ni][3] + bv);
        vpk[mi][ni][0] = u0.i;
        vpk[mi][ni][1] = u1.i;
      }
    }

    // -------- S^T = K * Q^T  (M=64 key, N=64 q, K=32) + softmax --------
    int pk[4][4][2];
    float rv[4];
    {
      f32x4 s[4][4];
#pragma unroll
      for (int MI = 0; MI < 4; ++MI)
#pragma unroll
        for (int ni = 0; ni < 4; ++ni) s[MI][ni] = (f32x4)0.0f;
#pragma unroll
      for (int ni = 0; ni < 4; ++ni) {
        const half8 qb = xpose8(qtp[0][ni][0], qtp[0][ni][1], qtp[1][ni][0], qtp[1][ni][1],
                                srcA, srcB, misel);
#pragma unroll
        for (int MI = 0; MI < 4; ++MI)
          s[MI][ni] = __builtin_amdgcn_mfma_f32_16x16x32_f16(ka[MI], qb, s[MI][ni], 0, 0, 0);
      }

      const float alpha = 0.17677669529663687f;   // 1/sqrt(32)
#pragma unroll
      for (int ni = 0; ni < 4; ++ni) {
        float m = s[0][ni][0];
#pragma unroll
        for (int MI = 0; MI < 4; ++MI)
#pragma unroll
          for (int r = 0; r < 4; ++r) m = fmaxf(m, s[MI][ni][r]);
        m = fmaxf(m, __shfl_xor(m, 16, 64));
        m = fmaxf(m, __shfl_xor(m, 32, 64));
        float sum = 0.0f;
#pragma unroll
        for (int MI = 0; MI < 4; ++MI)
#pragma unroll
          for (int r = 0; r < 4; ++r) {
            const float e = __expf((s[MI][ni][r] - m) * alpha);
            sum += e;
            s[MI][ni][r] = e;
          }
        sum += __shfl_xor(sum, 16, 64);
        sum += __shfl_xor(sum, 32, 64);
        rv[ni] = 1.0f / sum;
#pragma unroll
        for (int MI = 0; MI < 4; ++MI) {
          PKU u0, u1;
          u0.h = __builtin_amdgcn_cvt_pkrtz(s[MI][ni][0], s[MI][ni][1]);
          u1.h = __builtin_amdgcn_cvt_pkrtz(s[MI][ni][2], s[MI][ni][3]);
          pk[MI][ni][0] = u0.i;
          pk[MI][ni][1] = u1.i;
        }
      }
    }

    // -------- O^T = V^T * P^T   (M=32 d, N=64 q, K=64), pack immediately --------
    {
      f32x4 oh[2][4];
#pragma unroll
      for (int MI = 0; MI < 2; ++MI)
#pragma unroll
        for (int ni = 0; ni < 4; ++ni) oh[MI][ni] = (f32x4)0.0f;
#pragma unroll
      for (int kk = 0; kk < 2; ++kk) {
        half8 va[2];
#pragma unroll
        for (int MI = 0; MI < 2; ++MI)
          va[MI] = xpose8(vpk[2*kk][MI][0], vpk[2*kk][MI][1],
                          vpk[2*kk+1][MI][0], vpk[2*kk+1][MI][1], srcA, srcB, misel);
#pragma unroll
        for (int ni = 0; ni < 4; ++ni) {
          const half8 pb = xpose8(pk[2*kk][ni][0], pk[2*kk][ni][1],
                                  pk[2*kk+1][ni][0], pk[2*kk+1][ni][1], srcA, srcB, misel);
#pragma unroll
          for (int MI = 0; MI < 2; ++MI)
            oh[MI][ni] = __builtin_amdgcn_mfma_f32_16x16x32_f16(va[MI], pb, oh[MI][ni], 0, 0, 0);
        }
      }
#pragma unroll
      for (int MI = 0; MI < 2; ++MI)
#pragma unroll
        for (int ni = 0; ni < 4; ++ni) {
          PK2 u;
          u.h[0] = __builtin_amdgcn_cvt_pkrtz(oh[MI][ni][0] * rv[ni], oh[MI][ni][1] * rv[ni]);
          u.h[1] = __builtin_amdgcn_cvt_pkrtz(oh[MI][ni][2] * rv[ni], oh[MI][ni][3] * rv[ni]);
          ohp[hi][MI][ni][0] = u.i[0];
          ohp[hi][MI][ni][1] = u.i[1];
        }
    }
  }

  __syncthreads();   // all waves done reading tok

  // ---------------- write attention output into LDS (aliases tok), b64 ----------------
#pragma unroll
  for (int hi = 0; hi < 2; ++hi) {
    const int hd = 2*w + hi;
#pragma unroll
    for (int MI = 0; MI < 2; ++MI)
#pragma unroll
      for (int ni = 0; ni < 4; ++ni) {
        PK2 u;
        u.i[0] = ohp[hi][MI][ni][0];
        u.i[1] = ohp[hi][MI][ni][1];
        *(half4_t*)(tok + tokIdx(ni*16 + l15, hd*32 + MI*16 + g*4)) = u.h4;
      }
  }
  __syncthreads();

  // ---------------- proj: out = AO * Wp^T + bp  (M=64, N=64/wave, K=256) ----------------
  f32x4 pa[4][4];
#pragma unroll
  for (int mi = 0; mi < 4; ++mi)
#pragma unroll
    for (int ni = 0; ni < 4; ++ni) pa[mi][ni] = (f32x4)0.0f;

#pragma unroll
  for (int kk = 0; kk < 8; ++kk) {
    half8 af[4], bf[4];
#pragma unroll
    for (int mi = 0; mi < 4; ++mi)
      af[mi] = *(const half8*)(tok + tokIdx(mi*16 + l15, kk*32 + g*8));
#pragma unroll
    for (int ni = 0; ni < 4; ++ni)
      bf[ni] = *(const half8*)(wproj16 + (w*64 + ni*16 + l15)*256 + kk*32 + g*8);
#pragma unroll
    for (int mi = 0; mi < 4; ++mi)
#pragma unroll
      for (int ni = 0; ni < 4; ++ni)
        pa[mi][ni] = __builtin_amdgcn_mfma_f32_16x16x32_f16(af[mi], bf[ni], pa[mi][ni], 0, 0, 0);
  }

#pragma unroll
  for (int ni = 0; ni < 4; ++ni) {
    const float bb = b_proj[w*64 + ni*16 + l15];
#pragma unroll
    for (int mi = 0; mi < 4; ++mi)
#pragma unroll
      for (int r = 0; r < 4; ++r) pa[mi][ni][r] += bb;
  }

  // ---------------- staged vectorized output: 2 passes of 32 rows ----------------
  float* tokF = (float*)tok;   // [32][256] f32, swizzled (aliases tok)
#pragma unroll
  for (int p = 0; p < 2; ++p) {
    __syncthreads();   // p=0: proj reads of tok done; p=1: pass-0 reads done
#pragma unroll
    for (int mh = 0; mh < 2; ++mh) {
      const int mi = 2*p + mh;
#pragma unroll
      for (int ni = 0; ni < 4; ++ni)
#pragma unroll
        for (int r = 0; r < 4; ++r) {
          const int tr = mh*16 + g*4 + r;
          tokF[tr*256 + ((w*64 + ni*16 + l15) ^ ((tr & 7) << 2))] = pa[mi][ni][r];
        }
    }
    __syncthreads();
    const int tr = w*8 + (lane >> 3);          // row within pass
    const int t  = p*32 + tr;                  // token
    const long long rowbase = base + ((long long)(t >> 3)*192 + (t & 7))*256;
#pragma unroll
    for (int k = 0; k < 8; ++k) {
      const int c = (lane & 7)*4 + k*32;
      const f32x4 v4 = *(const f32x4*)(tokF + tr*256 + (c ^ ((tr & 7) << 2)));
      *(f32x4*)(out + rowbase + c) = v4;
    }
  }
}

extern "C" void kernel_launch(void* const* d_in, const int* in_sizes, int n_in,
                              void* d_out, int out_size, void* d_ws, size_t ws_size,
                              hipStream_t stream) {
  const float* x      = (const float*)d_in[0];
  const float* w_qkv  = (const float*)d_in[1];
  const float* b_qkv  = (const float*)d_in[2];
  const float* w_proj = (const float*)d_in[3];
  const float* b_proj = (const float*)d_in[4];
  float* out = (float*)d_out;
  _Float16* w16 = (_Float16*)d_ws;

  wconv_kernel<<<1024, 256, 0, stream>>>(w_qkv, w_proj, w16);
  attn_kernel<<<4608, 256, 0, stream>>>(x, b_qkv, b_proj, w16, out);
}

// Round 7
// 367.536 us; speedup vs baseline: 2.3817x; 1.4419x over previous
//
#include <hip/hip_runtime.h>

typedef _Float16 half8  __attribute__((ext_vector_type(8)));
typedef _Float16 half4_t __attribute__((ext_vector_type(4)));
typedef __fp16   fp16x2 __attribute__((ext_vector_type(2)));
typedef float    f32x4  __attribute__((ext_vector_type(4)));

union I4H8 { int i[4]; half8 h; };
union PKU  { fp16x2 h; int i; };
union PK2  { fp16x2 h[2]; int i[2]; half4_t h4; };

// swizzled token-LDS index (halves). XOR bits are multiples of 8 halves (16 B),
// so 16B ds_read_b128 chunks stay contiguous; 4-half runs (8B) also survive.
__device__ __forceinline__ int tokIdx(int r, int c) { return r*256 + (c ^ ((r & 7) << 3)); }

// C-fragment (rows in-reg, cols on l15) -> A/B-fragment (cols in-reg, rows kept on l15).
__device__ __forceinline__ half8 xpose8(int a0, int a1, int b0, int b1,
                                        int sA, int sB, bool msel) {
  const int t0 = __shfl(a0, sA, 64);
  const int t1 = __shfl(b0, sA, 64);
  const int t2 = __shfl(a1, sA, 64);
  const int t3 = __shfl(b1, sA, 64);
  const int t4 = __shfl(a0, sB, 64);
  const int t5 = __shfl(b0, sB, 64);
  const int t6 = __shfl(a1, sB, 64);
  const int t7 = __shfl(b1, sB, 64);
  I4H8 u;
  u.i[0] = msel ? t1 : t0;
  u.i[1] = msel ? t3 : t2;
  u.i[2] = msel ? t5 : t4;
  u.i[3] = msel ? t7 : t6;
  return u.h;
}

__global__ void __launch_bounds__(256)
wconv_kernel(const float* __restrict__ wq, const float* __restrict__ wp,
             _Float16* __restrict__ o)
{
  const int i = blockIdx.x * 256 + threadIdx.x;
  if (i < 768*256) o[i] = (_Float16)wq[i];
  else             o[i] = (_Float16)wp[i - 768*256];
}

// 256 threads = 4 waves; 2 heads per wave; one 8x8 window per block.
// (256,2): proven no-spill config — unified (arch+acc) budget 256/wave.
__global__ void __launch_bounds__(256, 2)
attn_kernel(const float* __restrict__ x,
            const float* __restrict__ b_qkv,
            const float* __restrict__ b_proj,
            const _Float16* __restrict__ w16,
            float* __restrict__ out)
{
  __shared__ __align__(16) _Float16 tok[64*256];   // 32 KB total LDS

  const int tid  = threadIdx.x;
  const int lane = tid & 63;
  const int w    = tid >> 6;
  const int l15  = lane & 15;
  const int g    = lane >> 4;

  const int wid = blockIdx.x;
  const int b   = wid / (24*24);
  const int wh  = (wid / 24) % 24;
  const int ww  = wid % 24;
  const long long base = (((long long)b*192 + wh*8)*192 + ww*8)*256;

  // ---------------- stage tokens -> LDS fp16 (swizzled); 16 rows/wave ----------------
#pragma unroll
  for (int i = 0; i < 16; ++i) {
    const int tk = w*16 + i;
    const float4 v = *(const float4*)(x + base + ((tk >> 3)*192 + (tk & 7))*256 + lane*4);
    half4_t h;
    h[0] = (_Float16)v.x; h[1] = (_Float16)v.y;
    h[2] = (_Float16)v.z; h[3] = (_Float16)v.w;
    *(half4_t*)(tok + tk*256 + ((lane*4) ^ ((tk & 7) << 3))) = h;
  }
  __syncthreads();

  const _Float16* wqkv16  = w16;
  const _Float16* wproj16 = w16 + 768*256;

  const int srcA  = l15 | ((2*(g & 1)    ) << 4);
  const int srcB  = l15 | ((2*(g & 1) + 1) << 4);
  const bool misel = (g >> 1) != 0;

  int ohp[2][2][4][2];   // packed fp16 O^T fragments, both heads (32 ints)

#pragma unroll
  for (int hi = 0; hi < 2; ++hi) {
    const int hd = 2*w + hi;

    // ======== merged QKV:  Q^T,K^T = W*X^T (M=32 d, N=64)  and  V = X*Wv^T (M=64, N=32 d)
    // tok fragments bt[] serve as B for Q/K and as A for V (identical layouts).
    f32x4 qa[2][4], kc[2][4], vv[4][2];
#pragma unroll
    for (int mi = 0; mi < 2; ++mi)
#pragma unroll
      for (int ni = 0; ni < 4; ++ni) { qa[mi][ni] = (f32x4)0.0f; kc[mi][ni] = (f32x4)0.0f; }
#pragma unroll
    for (int mi = 0; mi < 4; ++mi)
#pragma unroll
      for (int ni = 0; ni < 2; ++ni) vv[mi][ni] = (f32x4)0.0f;

#pragma unroll
    for (int kk = 0; kk < 8; ++kk) {
      half8 bt[4], aw[4], wv[2];
#pragma unroll
      for (int ni = 0; ni < 4; ++ni)
        bt[ni] = *(const half8*)(tok + tokIdx(ni*16 + l15, kk*32 + g*8));
#pragma unroll
      for (int mi = 0; mi < 2; ++mi) {
        aw[mi]     = *(const half8*)(wqkv16 + (      hd*32 + mi*16 + l15)*256 + kk*32 + g*8);
        aw[2 + mi] = *(const half8*)(wqkv16 + (256 + hd*32 + mi*16 + l15)*256 + kk*32 + g*8);
        wv[mi]     = *(const half8*)(wqkv16 + (512 + hd*32 + mi*16 + l15)*256 + kk*32 + g*8);
      }
      __builtin_amdgcn_s_setprio(1);
#pragma unroll
      for (int mi = 0; mi < 2; ++mi)
#pragma unroll
        for (int ni = 0; ni < 4; ++ni) {
          qa[mi][ni] = __builtin_amdgcn_mfma_f32_16x16x32_f16(aw[mi],     bt[ni], qa[mi][ni], 0, 0, 0);
          kc[mi][ni] = __builtin_amdgcn_mfma_f32_16x16x32_f16(aw[2 + mi], bt[ni], kc[mi][ni], 0, 0, 0);
        }
#pragma unroll
      for (int mi = 0; mi < 4; ++mi)
#pragma unroll
        for (int ni = 0; ni < 2; ++ni)
          vv[mi][ni] = __builtin_amdgcn_mfma_f32_16x16x32_f16(bt[mi], wv[ni], vv[mi][ni], 0, 0, 0);
      __builtin_amdgcn_s_setprio(0);
    }

    // pack Q^T (rows = d in-reg) with bias
    int qtp[2][4][2];
#pragma unroll
    for (int mi = 0; mi < 2; ++mi) {
      float bq[4];
#pragma unroll
      for (int r = 0; r < 4; ++r) bq[r] = b_qkv[hd*32 + mi*16 + g*4 + r];
#pragma unroll
      for (int ni = 0; ni < 4; ++ni) {
        PKU u0, u1;
        u0.h = __builtin_amdgcn_cvt_pkrtz(qa[mi][ni][0] + bq[0], qa[mi][ni][1] + bq[1]);
        u1.h = __builtin_amdgcn_cvt_pkrtz(qa[mi][ni][2] + bq[2], qa[mi][ni][3] + bq[3]);
        qtp[mi][ni][0] = u0.i; qtp[mi][ni][1] = u1.i;
      }
    }

    // pack K^T with bias, transpose to S-GEMM A-fragments (rows = key tokens)
    half8 ka[4];
    {
      int ktp[2][4][2];
#pragma unroll
      for (int mi = 0; mi < 2; ++mi) {
        float bk[4];
#pragma unroll
        for (int r = 0; r < 4; ++r) bk[r] = b_qkv[256 + hd*32 + mi*16 + g*4 + r];
#pragma unroll
        for (int ni = 0; ni < 4; ++ni) {
          PKU u0, u1;
          u0.h = __builtin_amdgcn_cvt_pkrtz(kc[mi][ni][0] + bk[0], kc[mi][ni][1] + bk[1]);
          u1.h = __builtin_amdgcn_cvt_pkrtz(kc[mi][ni][2] + bk[2], kc[mi][ni][3] + bk[3]);
          ktp[mi][ni][0] = u0.i; ktp[mi][ni][1] = u1.i;
        }
      }
#pragma unroll
      for (int MI = 0; MI < 4; ++MI)
        ka[MI] = xpose8(ktp[0][MI][0], ktp[0][MI][1], ktp[1][MI][0], ktp[1][MI][1],
                        srcA, srcB, misel);
    }

    // pack V (rows = tok in-reg, cols = d on l15) with col-indexed bias
    int vpk[4][2][2];
#pragma unroll
    for (int ni = 0; ni < 2; ++ni) {
      const float bv = b_qkv[512 + hd*32 + ni*16 + l15];
#pragma unroll
      for (int mi = 0; mi < 4; ++mi) {
        PKU u0, u1;
        u0.h = __builtin_amdgcn_cvt_pkrtz(vv[mi][ni][0] + bv, vv[mi][ni][1] + bv);
        u1.h = __builtin_amdgcn_cvt_pkrtz(vv[mi][ni][2] + bv, vv[mi][ni][3] + bv);
        vpk[mi][ni][0] = u0.i;
        vpk[mi][ni][1] = u1.i;
      }
    }

    // -------- S^T = K * Q^T  (M=64 key, N=64 q, K=32) + softmax --------
    int pk[4][4][2];
    float rv[4];
    {
      f32x4 s[4][4];
#pragma unroll
      for (int MI = 0; MI < 4; ++MI)
#pragma unroll
        for (int ni = 0; ni < 4; ++ni) s[MI][ni] = (f32x4)0.0f;
#pragma unroll
      for (int ni = 0; ni < 4; ++ni) {
        const half8 qb = xpose8(qtp[0][ni][0], qtp[0][ni][1], qtp[1][ni][0], qtp[1][ni][1],
                                srcA, srcB, misel);
#pragma unroll
        for (int MI = 0; MI < 4; ++MI)
          s[MI][ni] = __builtin_amdgcn_mfma_f32_16x16x32_f16(ka[MI], qb, s[MI][ni], 0, 0, 0);
      }

      const float alpha = 0.17677669529663687f;   // 1/sqrt(32)
#pragma unroll
      for (int ni = 0; ni < 4; ++ni) {
        float m = s[0][ni][0];
#pragma unroll
        for (int MI = 0; MI < 4; ++MI)
#pragma unroll
          for (int r = 0; r < 4; ++r) m = fmaxf(m, s[MI][ni][r]);
        m = fmaxf(m, __shfl_xor(m, 16, 64));
        m = fmaxf(m, __shfl_xor(m, 32, 64));
        float sum = 0.0f;
#pragma unroll
        for (int MI = 0; MI < 4; ++MI)
#pragma unroll
          for (int r = 0; r < 4; ++r) {
            const float e = __expf((s[MI][ni][r] - m) * alpha);
            sum += e;
            s[MI][ni][r] = e;
          }
        sum += __shfl_xor(sum, 16, 64);
        sum += __shfl_xor(sum, 32, 64);
        rv[ni] = 1.0f / sum;
#pragma unroll
        for (int MI = 0; MI < 4; ++MI) {
          PKU u0, u1;
          u0.h = __builtin_amdgcn_cvt_pkrtz(s[MI][ni][0], s[MI][ni][1]);
          u1.h = __builtin_amdgcn_cvt_pkrtz(s[MI][ni][2], s[MI][ni][3]);
          pk[MI][ni][0] = u0.i;
          pk[MI][ni][1] = u1.i;
        }
      }
    }

    // -------- O^T = V^T * P^T   (M=32 d, N=64 q, K=64), pack immediately --------
    {
      f32x4 oh[2][4];
#pragma unroll
      for (int MI = 0; MI < 2; ++MI)
#pragma unroll
        for (int ni = 0; ni < 4; ++ni) oh[MI][ni] = (f32x4)0.0f;
#pragma unroll
      for (int kk = 0; kk < 2; ++kk) {
        half8 va[2];
#pragma unroll
        for (int MI = 0; MI < 2; ++MI)
          va[MI] = xpose8(vpk[2*kk][MI][0], vpk[2*kk][MI][1],
                          vpk[2*kk+1][MI][0], vpk[2*kk+1][MI][1], srcA, srcB, misel);
#pragma unroll
        for (int ni = 0; ni < 4; ++ni) {
          const half8 pb = xpose8(pk[2*kk][ni][0], pk[2*kk][ni][1],
                                  pk[2*kk+1][ni][0], pk[2*kk+1][ni][1], srcA, srcB, misel);
#pragma unroll
          for (int MI = 0; MI < 2; ++MI)
            oh[MI][ni] = __builtin_amdgcn_mfma_f32_16x16x32_f16(va[MI], pb, oh[MI][ni], 0, 0, 0);
        }
      }
#pragma unroll
      for (int MI = 0; MI < 2; ++MI)
#pragma unroll
        for (int ni = 0; ni < 4; ++ni) {
          PK2 u;
          u.h[0] = __builtin_amdgcn_cvt_pkrtz(oh[MI][ni][0] * rv[ni], oh[MI][ni][1] * rv[ni]);
          u.h[1] = __builtin_amdgcn_cvt_pkrtz(oh[MI][ni][2] * rv[ni], oh[MI][ni][3] * rv[ni]);
          ohp[hi][MI][ni][0] = u.i[0];
          ohp[hi][MI][ni][1] = u.i[1];
        }
    }
  }

  __syncthreads();   // all waves done reading tok

  // ---------------- write attention output into LDS (aliases tok), b64 ----------------
#pragma unroll
  for (int hi = 0; hi < 2; ++hi) {
    const int hd = 2*w + hi;
#pragma unroll
    for (int MI = 0; MI < 2; ++MI)
#pragma unroll
      for (int ni = 0; ni < 4; ++ni) {
        PK2 u;
        u.i[0] = ohp[hi][MI][ni][0];
        u.i[1] = ohp[hi][MI][ni][1];
        *(half4_t*)(tok + tokIdx(ni*16 + l15, hd*32 + MI*16 + g*4)) = u.h4;
      }
  }
  __syncthreads();

  // ---------------- proj: out = AO * Wp^T + bp  (M=64, N=64/wave, K=256) ----------------
  f32x4 pa[4][4];
#pragma unroll
  for (int mi = 0; mi < 4; ++mi)
#pragma unroll
    for (int ni = 0; ni < 4; ++ni) pa[mi][ni] = (f32x4)0.0f;

#pragma unroll
  for (int kk = 0; kk < 8; ++kk) {
    half8 af[4], bf[4];
#pragma unroll
    for (int mi = 0; mi < 4; ++mi)
      af[mi] = *(const half8*)(tok + tokIdx(mi*16 + l15, kk*32 + g*8));
#pragma unroll
    for (int ni = 0; ni < 4; ++ni)
      bf[ni] = *(const half8*)(wproj16 + (w*64 + ni*16 + l15)*256 + kk*32 + g*8);
    __builtin_amdgcn_s_setprio(1);
#pragma unroll
    for (int mi = 0; mi < 4; ++mi)
#pragma unroll
      for (int ni = 0; ni < 4; ++ni)
        pa[mi][ni] = __builtin_amdgcn_mfma_f32_16x16x32_f16(af[mi], bf[ni], pa[mi][ni], 0, 0, 0);
    __builtin_amdgcn_s_setprio(0);
  }

#pragma unroll
  for (int ni = 0; ni < 4; ++ni) {
    const float bb = b_proj[w*64 + ni*16 + l15];
#pragma unroll
    for (int mi = 0; mi < 4; ++mi)
#pragma unroll
      for (int r = 0; r < 4; ++r) pa[mi][ni][r] += bb;
  }

  // ---------------- staged output: 2 passes of 32 rows; 1KB-contiguous row stores ----------------
  float* tokF = (float*)tok;   // [32][256] f32, swizzled (aliases tok)
#pragma unroll
  for (int p = 0; p < 2; ++p) {
    __syncthreads();   // p=0: proj reads of tok done; p=1: pass-0 reads done
#pragma unroll
    for (int mh = 0; mh < 2; ++mh) {
      const int mi = 2*p + mh;
#pragma unroll
      for (int ni = 0; ni < 4; ++ni)
#pragma unroll
        for (int r = 0; r < 4; ++r) {
          const int tr = mh*16 + g*4 + r;
          tokF[tr*256 + ((w*64 + ni*16 + l15) ^ ((tr & 7) << 2))] = pa[mi][ni][r];
        }
    }
    __syncthreads();
    // each wave stores 8 full token rows: 64 lanes x 16B = 1024B contiguous per store
#pragma unroll
    for (int i = 0; i < 8; ++i) {
      const int tr = w*8 + i;
      const int t  = p*32 + tr;
      const long long rowbase = base + ((long long)(t >> 3)*192 + (t & 7))*256;
      const f32x4 v4 = *(const f32x4*)(tokF + tr*256 + ((lane*4) ^ ((tr & 7) << 2)));
      *(f32x4*)(out + rowbase + lane*4) = v4;
    }
  }
}

extern "C" void kernel_launch(void* const* d_in, const int* in_sizes, int n_in,
                              void* d_out, int out_size, void* d_ws, size_t ws_size,
                              hipStream_t stream) {
  const float* x      = (const float*)d_in[0];
  const float* w_qkv  = (const float*)d_in[1];
  const float* b_qkv  = (const float*)d_in[2];
  const float* w_proj = (const float*)d_in[3];
  const float* b_proj = (const float*)d_in[4];
  float* out = (float*)d_out;
  _Float16* w16 = (_Float16*)d_ws;

  wconv_kernel<<<1024, 256, 0, stream>>>(w_qkv, w_proj, w16);
  attn_kernel<<<4608, 256, 0, stream>>>(x, b_qkv, b_proj, w16, out);
}

// Round 8
// 356.473 us; speedup vs baseline: 2.4556x; 1.0310x over previous
//
#include <hip/hip_runtime.h>

typedef _Float16 half8  __attribute__((ext_vector_type(8)));
typedef _Float16 half4_t __attribute__((ext_vector_type(4)));
typedef __fp16   fp16x2 __attribute__((ext_vector_type(2)));
typedef float    f32x4  __attribute__((ext_vector_type(4)));

union PKU  { fp16x2 h; int i; };
union PK2  { fp16x2 h[2]; int i[2]; half4_t h4; };

__device__ __forceinline__ half4_t mk4(int a, int b) {
  PK2 u; u.i[0] = a; u.i[1] = b; return u.h4;
}

// swizzled token-LDS index (halves). XOR bits are multiples of 8 halves (16 B),
// so 16B ds_read_b128 chunks stay contiguous; 4-half runs (8B) also survive.
__device__ __forceinline__ int tokIdx(int r, int c) { return r*256 + (c ^ ((r & 7) << 3)); }

__global__ void __launch_bounds__(256)
wconv_kernel(const float* __restrict__ wq, const float* __restrict__ wp,
             _Float16* __restrict__ o)
{
  const int i = blockIdx.x * 256 + threadIdx.x;
  if (i < 768*256) o[i] = (_Float16)wq[i];
  else             o[i] = (_Float16)wp[i - 768*256];
}

// 256 threads = 4 waves; 2 heads per wave; one 8x8 window per block.
// (256,2): proven no-spill config — unified (arch+acc) budget 256/wave.
// S and PV consume Q/K/V C-fragments DIRECTLY via K=16 MFMAs (operand k-layout
// g*4+j == C-frag row-layout g*4+reg) — zero cross-lane transposes.
__global__ void __launch_bounds__(256, 2)
attn_kernel(const float* __restrict__ x,
            const float* __restrict__ b_qkv,
            const float* __restrict__ b_proj,
            const _Float16* __restrict__ w16,
            float* __restrict__ out)
{
  __shared__ __align__(16) _Float16 tok[64*256];   // 32 KB total LDS

  const int tid  = threadIdx.x;
  const int lane = tid & 63;
  const int w    = tid >> 6;
  const int l15  = lane & 15;
  const int g    = lane >> 4;

  const int wid = blockIdx.x;
  const int b   = wid / (24*24);
  const int wh  = (wid / 24) % 24;
  const int ww  = wid % 24;
  const long long base = (((long long)b*192 + wh*8)*192 + ww*8)*256;

  // ---------------- stage tokens -> LDS fp16 (swizzled); 16 rows/wave ----------------
#pragma unroll
  for (int i = 0; i < 16; ++i) {
    const int tk = w*16 + i;
    const float4 v = *(const float4*)(x + base + ((tk >> 3)*192 + (tk & 7))*256 + lane*4);
    half4_t h;
    h[0] = (_Float16)v.x; h[1] = (_Float16)v.y;
    h[2] = (_Float16)v.z; h[3] = (_Float16)v.w;
    *(half4_t*)(tok + tk*256 + ((lane*4) ^ ((tk & 7) << 3))) = h;
  }
  __syncthreads();

  const _Float16* wqkv16  = w16;
  const _Float16* wproj16 = w16 + 768*256;

  int ohp[2][2][4][2];   // packed fp16 O^T fragments, both heads (32 ints)

#pragma unroll
  for (int hi = 0; hi < 2; ++hi) {
    const int hd = 2*w + hi;

    // ======== merged QKV:  Q^T,K^T = W*X^T (M=32 d, N=64)  and  V = X*Wv^T (M=64, N=32 d)
    // tok fragments bt[] serve as B for Q/K and as A for V (identical layouts).
    f32x4 qa[2][4], kc[2][4], vv[4][2];
#pragma unroll
    for (int mi = 0; mi < 2; ++mi)
#pragma unroll
      for (int ni = 0; ni < 4; ++ni) { qa[mi][ni] = (f32x4)0.0f; kc[mi][ni] = (f32x4)0.0f; }
#pragma unroll
    for (int mi = 0; mi < 4; ++mi)
#pragma unroll
      for (int ni = 0; ni < 2; ++ni) vv[mi][ni] = (f32x4)0.0f;

#pragma unroll
    for (int kk = 0; kk < 8; ++kk) {
      half8 bt[4], aw[4], wv[2];
#pragma unroll
      for (int ni = 0; ni < 4; ++ni)
        bt[ni] = *(const half8*)(tok + tokIdx(ni*16 + l15, kk*32 + g*8));
#pragma unroll
      for (int mi = 0; mi < 2; ++mi) {
        aw[mi]     = *(const half8*)(wqkv16 + (      hd*32 + mi*16 + l15)*256 + kk*32 + g*8);
        aw[2 + mi] = *(const half8*)(wqkv16 + (256 + hd*32 + mi*16 + l15)*256 + kk*32 + g*8);
        wv[mi]     = *(const half8*)(wqkv16 + (512 + hd*32 + mi*16 + l15)*256 + kk*32 + g*8);
      }
      __builtin_amdgcn_s_setprio(1);
#pragma unroll
      for (int mi = 0; mi < 2; ++mi)
#pragma unroll
        for (int ni = 0; ni < 4; ++ni) {
          qa[mi][ni] = __builtin_amdgcn_mfma_f32_16x16x32_f16(aw[mi],     bt[ni], qa[mi][ni], 0, 0, 0);
          kc[mi][ni] = __builtin_amdgcn_mfma_f32_16x16x32_f16(aw[2 + mi], bt[ni], kc[mi][ni], 0, 0, 0);
        }
#pragma unroll
      for (int mi = 0; mi < 4; ++mi)
#pragma unroll
        for (int ni = 0; ni < 2; ++ni)
          vv[mi][ni] = __builtin_amdgcn_mfma_f32_16x16x32_f16(bt[mi], wv[ni], vv[mi][ni], 0, 0, 0);
      __builtin_amdgcn_s_setprio(0);
    }

    // pack Q^T (d rows in-reg) with bias: qtp[kk2][ni] = B-frag for S (k=d slice kk2)
    int qtp[2][4][2];
#pragma unroll
    for (int mi = 0; mi < 2; ++mi) {
      float bq[4];
#pragma unroll
      for (int r = 0; r < 4; ++r) bq[r] = b_qkv[hd*32 + mi*16 + g*4 + r];
#pragma unroll
      for (int ni = 0; ni < 4; ++ni) {
        PKU u0, u1;
        u0.h = __builtin_amdgcn_cvt_pkrtz(qa[mi][ni][0] + bq[0], qa[mi][ni][1] + bq[1]);
        u1.h = __builtin_amdgcn_cvt_pkrtz(qa[mi][ni][2] + bq[2], qa[mi][ni][3] + bq[3]);
        qtp[mi][ni][0] = u0.i; qtp[mi][ni][1] = u1.i;
      }
    }

    // pack K^T (d rows in-reg) with bias: kcp[kk2][KB] = A-frag for S (keys on l15)
    int kcp[2][4][2];
#pragma unroll
    for (int mi = 0; mi < 2; ++mi) {
      float bk[4];
#pragma unroll
      for (int r = 0; r < 4; ++r) bk[r] = b_qkv[256 + hd*32 + mi*16 + g*4 + r];
#pragma unroll
      for (int ni = 0; ni < 4; ++ni) {
        PKU u0, u1;
        u0.h = __builtin_amdgcn_cvt_pkrtz(kc[mi][ni][0] + bk[0], kc[mi][ni][1] + bk[1]);
        u1.h = __builtin_amdgcn_cvt_pkrtz(kc[mi][ni][2] + bk[2], kc[mi][ni][3] + bk[3]);
        kcp[mi][ni][0] = u0.i; kcp[mi][ni][1] = u1.i;
      }
    }

    // pack V (tok rows in-reg, d on l15) with col-indexed bias: vpk[kk2][MI] = A-frag for PV
    int vpk[4][2][2];
#pragma unroll
    for (int ni = 0; ni < 2; ++ni) {
      const float bv = b_qkv[512 + hd*32 + ni*16 + l15];
#pragma unroll
      for (int mi = 0; mi < 4; ++mi) {
        PKU u0, u1;
        u0.h = __builtin_amdgcn_cvt_pkrtz(vv[mi][ni][0] + bv, vv[mi][ni][1] + bv);
        u1.h = __builtin_amdgcn_cvt_pkrtz(vv[mi][ni][2] + bv, vv[mi][ni][3] + bv);
        vpk[mi][ni][0] = u0.i;
        vpk[mi][ni][1] = u1.i;
      }
    }

    // -------- S^T = K * Q^T  (M=64 key, N=64 q, Kdim=32) via K=16 MFMA, no transposes --------
    int pk[4][4][2];
    float rv[4];
    {
      f32x4 s[4][4];
#pragma unroll
      for (int MI = 0; MI < 4; ++MI)
#pragma unroll
        for (int ni = 0; ni < 4; ++ni) s[MI][ni] = (f32x4)0.0f;
      __builtin_amdgcn_s_setprio(1);
#pragma unroll
      for (int kk2 = 0; kk2 < 2; ++kk2)
#pragma unroll
        for (int ni = 0; ni < 4; ++ni) {
          const half4_t qb = mk4(qtp[kk2][ni][0], qtp[kk2][ni][1]);
#pragma unroll
          for (int MI = 0; MI < 4; ++MI)
            s[MI][ni] = __builtin_amdgcn_mfma_f32_16x16x16f16(
                mk4(kcp[kk2][MI][0], kcp[kk2][MI][1]), qb, s[MI][ni], 0, 0, 0);
        }
      __builtin_amdgcn_s_setprio(0);

      const float alpha = 0.17677669529663687f;   // 1/sqrt(32)
#pragma unroll
      for (int ni = 0; ni < 4; ++ni) {
        float m = s[0][ni][0];
#pragma unroll
        for (int MI = 0; MI < 4; ++MI)
#pragma unroll
          for (int r = 0; r < 4; ++r) m = fmaxf(m, s[MI][ni][r]);
        m = fmaxf(m, __shfl_xor(m, 16, 64));
        m = fmaxf(m, __shfl_xor(m, 32, 64));
        float sum = 0.0f;
#pragma unroll
        for (int MI = 0; MI < 4; ++MI)
#pragma unroll
          for (int r = 0; r < 4; ++r) {
            const float e = __expf((s[MI][ni][r] - m) * alpha);
            sum += e;
            s[MI][ni][r] = e;
          }
        sum += __shfl_xor(sum, 16, 64);
        sum += __shfl_xor(sum, 32, 64);
        rv[ni] = 1.0f / sum;
#pragma unroll
        for (int MI = 0; MI < 4; ++MI) {
          PKU u0, u1;
          u0.h = __builtin_amdgcn_cvt_pkrtz(s[MI][ni][0], s[MI][ni][1]);
          u1.h = __builtin_amdgcn_cvt_pkrtz(s[MI][ni][2], s[MI][ni][3]);
          pk[MI][ni][0] = u0.i;
          pk[MI][ni][1] = u1.i;
        }
      }
    }

    // -------- O^T = V^T * P^T (M=32 d, N=64 q, Kdim=64) via K=16 MFMA, no transposes --------
    {
      f32x4 oh[2][4];
#pragma unroll
      for (int MI = 0; MI < 2; ++MI)
#pragma unroll
        for (int ni = 0; ni < 4; ++ni) oh[MI][ni] = (f32x4)0.0f;
      __builtin_amdgcn_s_setprio(1);
#pragma unroll
      for (int kk2 = 0; kk2 < 4; ++kk2)
#pragma unroll
        for (int ni = 0; ni < 4; ++ni) {
          const half4_t pb = mk4(pk[kk2][ni][0], pk[kk2][ni][1]);
#pragma unroll
          for (int MI = 0; MI < 2; ++MI)
            oh[MI][ni] = __builtin_amdgcn_mfma_f32_16x16x16f16(
                mk4(vpk[kk2][MI][0], vpk[kk2][MI][1]), pb, oh[MI][ni], 0, 0, 0);
        }
      __builtin_amdgcn_s_setprio(0);
#pragma unroll
      for (int MI = 0; MI < 2; ++MI)
#pragma unroll
        for (int ni = 0; ni < 4; ++ni) {
          PK2 u;
          u.h[0] = __builtin_amdgcn_cvt_pkrtz(oh[MI][ni][0] * rv[ni], oh[MI][ni][1] * rv[ni]);
          u.h[1] = __builtin_amdgcn_cvt_pkrtz(oh[MI][ni][2] * rv[ni], oh[MI][ni][3] * rv[ni]);
          ohp[hi][MI][ni][0] = u.i[0];
          ohp[hi][MI][ni][1] = u.i[1];
        }
    }
  }

  __syncthreads();   // all waves done reading tok

  // ---------------- write attention output into LDS (aliases tok), b64 ----------------
#pragma unroll
  for (int hi = 0; hi < 2; ++hi) {
    const int hd = 2*w + hi;
#pragma unroll
    for (int MI = 0; MI < 2; ++MI)
#pragma unroll
      for (int ni = 0; ni < 4; ++ni) {
        PK2 u;
        u.i[0] = ohp[hi][MI][ni][0];
        u.i[1] = ohp[hi][MI][ni][1];
        *(half4_t*)(tok + tokIdx(ni*16 + l15, hd*32 + MI*16 + g*4)) = u.h4;
      }
  }
  __syncthreads();

  // ---------------- proj: out = AO * Wp^T + bp  (M=64, N=64/wave, K=256) ----------------
  f32x4 pa[4][4];
#pragma unroll
  for (int mi = 0; mi < 4; ++mi)
#pragma unroll
    for (int ni = 0; ni < 4; ++ni) pa[mi][ni] = (f32x4)0.0f;

#pragma unroll
  for (int kk = 0; kk < 8; ++kk) {
    half8 af[4], bf[4];
#pragma unroll
    for (int mi = 0; mi < 4; ++mi)
      af[mi] = *(const half8*)(tok + tokIdx(mi*16 + l15, kk*32 + g*8));
#pragma unroll
    for (int ni = 0; ni < 4; ++ni)
      bf[ni] = *(const half8*)(wproj16 + (w*64 + ni*16 + l15)*256 + kk*32 + g*8);
    __builtin_amdgcn_s_setprio(1);
#pragma unroll
    for (int mi = 0; mi < 4; ++mi)
#pragma unroll
      for (int ni = 0; ni < 4; ++ni)
        pa[mi][ni] = __builtin_amdgcn_mfma_f32_16x16x32_f16(af[mi], bf[ni], pa[mi][ni], 0, 0, 0);
    __builtin_amdgcn_s_setprio(0);
  }

#pragma unroll
  for (int ni = 0; ni < 4; ++ni) {
    const float bb = b_proj[w*64 + ni*16 + l15];
#pragma unroll
    for (int mi = 0; mi < 4; ++mi)
#pragma unroll
      for (int r = 0; r < 4; ++r) pa[mi][ni][r] += bb;
  }

  // ---------------- staged output: 2 passes of 32 rows; 1KB-contiguous row stores ----------------
  float* tokF = (float*)tok;   // [32][256] f32, swizzled (aliases tok)
#pragma unroll
  for (int p = 0; p < 2; ++p) {
    __syncthreads();   // p=0: proj reads of tok done; p=1: pass-0 reads done
#pragma unroll
    for (int mh = 0; mh < 2; ++mh) {
      const int mi = 2*p + mh;
#pragma unroll
      for (int ni = 0; ni < 4; ++ni)
#pragma unroll
        for (int r = 0; r < 4; ++r) {
          const int tr = mh*16 + g*4 + r;
          tokF[tr*256 + ((w*64 + ni*16 + l15) ^ ((tr & 7) << 2))] = pa[mi][ni][r];
        }
    }
    __syncthreads();
    // each wave stores 8 full token rows: 64 lanes x 16B = 1024B contiguous per store
#pragma unroll
    for (int i = 0; i < 8; ++i) {
      const int tr = w*8 + i;
      const int t  = p*32 + tr;
      const long long rowbase = base + ((long long)(t >> 3)*192 + (t & 7))*256;
      const f32x4 v4 = *(const f32x4*)(tokF + tr*256 + ((lane*4) ^ ((tr & 7) << 2)));
      *(f32x4*)(out + rowbase + lane*4) = v4;
    }
  }
}

extern "C" void kernel_launch(void* const* d_in, const int* in_sizes, int n_in,
                              void* d_out, int out_size, void* d_ws, size_t ws_size,
                              hipStream_t stream) {
  const float* x      = (const float*)d_in[0];
  const float* w_qkv  = (const float*)d_in[1];
  const float* b_qkv  = (const float*)d_in[2];
  const float* w_proj = (const float*)d_in[3];
  const float* b_proj = (const float*)d_in[4];
  float* out = (float*)d_out;
  _Float16* w16 = (_Float16*)d_ws;

  wconv_kernel<<<1024, 256, 0, stream>>>(w_qkv, w_proj, w16);
  attn_kernel<<<4608, 256, 0, stream>>>(x, b_qkv, b_proj, w16, out);
}